// Round 1
// baseline (8635.078 us; speedup 1.0000x reference)
//
#include <hip/hip_runtime.h>
#include <math.h>

// Problem constants (from reference)
constexpr int DEPTH = 12;
constexpr int E     = 256;
constexpr int Fdim  = 128;
constexpr int H     = 8;
constexpr int HD    = 32;
constexpr int N     = 257;   // 2F+1
constexpr int B     = 64;
constexpr int BN    = B * N; // 16448 = 257 * 64  (exactly 257 tiles of 64 rows)
constexpr int FFD   = 1024;
constexpr int UCNT  = 1000;

enum { EPI_PLAIN = 0, EPI_RESID = 1, EPI_GELU = 2, EPI_QKV = 3 };

__device__ __forceinline__ float gelu_exact(float z) {
  return 0.5f * z * (1.0f + erff(z * 0.70710678118654752440f));
}

// ---------------- embed: x[b,n,e] = gathered + positions ----------------
// block = 128 threads over f (coalesced table reads); grid = (E, B)
__global__ __launch_bounds__(128) void embed_kernel(
    const int* __restrict__ user, const int* __restrict__ item,
    const float* __restrict__ utab, const float* __restrict__ itab,
    const float* __restrict__ cls, const float* __restrict__ pos,
    float* __restrict__ x)
{
  const int e = blockIdx.x;
  const int b = blockIdx.y;
  const int f = threadIdx.x;
  const int uid = user[b];
  const int iid = item[b];
  const float uu = utab[((size_t)e * UCNT + uid) * Fdim + f];
  const float ii = itab[((size_t)e * UCNT + iid) * Fdim + f];
  x[((size_t)b * N + 1 + f) * E + e]        = uu + pos[(1 + f) * E + e];
  x[((size_t)b * N + 1 + Fdim + f) * E + e] = ii + pos[(1 + Fdim + f) * E + e];
  if (f == 0) x[((size_t)b * N) * E + e] = cls[e] + pos[e];
}

// ---------------- layernorm: one wave per row of 256 ----------------
__global__ __launch_bounds__(256) void ln_kernel(
    const float* __restrict__ x, float* __restrict__ y,
    const float* __restrict__ g, const float* __restrict__ b)
{
  const int wave = threadIdx.x >> 6, lane = threadIdx.x & 63;
  const int row  = blockIdx.x * 4 + wave;
  const float4 v = *(const float4*)(x + (size_t)row * E + lane * 4);
  float s = v.x + v.y + v.z + v.w;
  float q = v.x * v.x + v.y * v.y + v.z * v.z + v.w * v.w;
#pragma unroll
  for (int o = 32; o > 0; o >>= 1) { s += __shfl_xor(s, o); q += __shfl_xor(q, o); }
  const float mean = s * (1.0f / 256.0f);
  const float var  = q * (1.0f / 256.0f) - mean * mean;
  const float rstd = rsqrtf(var + 1e-5f);
  const float4 gg = *(const float4*)(g + lane * 4);
  const float4 bb = *(const float4*)(b + lane * 4);
  float4 o4;
  o4.x = (v.x - mean) * rstd * gg.x + bb.x;
  o4.y = (v.y - mean) * rstd * gg.y + bb.y;
  o4.z = (v.z - mean) * rstd * gg.z + bb.z;
  o4.w = (v.w - mean) * rstd * gg.w + bb.w;
  *(float4*)(y + (size_t)row * E + lane * 4) = o4;
}

// ---------------- fp32 tiled GEMM: C = A(BNxK) @ W(KxNC) + bias ----------------
// 64x128 block tile, 256 threads, 4x8 per-thread microtile, K-chunks of 16.
// Epilogues: PLAIN / RESID (out += z) / GELU / QKV (write (B,H,N,HD) layout).
template<int K, int NC, int EPI>
__global__ __launch_bounds__(256) void gemm_f32(
    const float* __restrict__ A, const float* __restrict__ W,
    const float* __restrict__ bias, float* __restrict__ out)
{
  __shared__ __align__(16) float As[16][68];   // +4 pad: 2-way-max bank conflicts, 16B-aligned rows
  __shared__ __align__(16) float Bs[16][128];
  const int t    = threadIdx.x;
  const int row0 = blockIdx.y * 64;
  const int col0 = blockIdx.x * 128;
  const int tx = t & 15;          // cols tx*8..+7
  const int ty = t >> 4;          // rows ty*4..+3
  const int lm = t >> 2;          // A-load row 0..63
  const int lk = (t & 3) << 2;    // A-load k offset {0,4,8,12}
  const int bkr = t >> 4;         // B-load k row 0..15
  const int bnc = (t & 15) << 3;  // B-load col offset

  float acc[4][8] = {};

  for (int k0 = 0; k0 < K; k0 += 16) {
    const float4 av  = *(const float4*)(A + (size_t)(row0 + lm) * K + k0 + lk);
    const float4 bv0 = *(const float4*)(W + (size_t)(k0 + bkr) * NC + col0 + bnc);
    const float4 bv1 = *(const float4*)(W + (size_t)(k0 + bkr) * NC + col0 + bnc + 4);
    __syncthreads();
    As[lk + 0][lm] = av.x;
    As[lk + 1][lm] = av.y;
    As[lk + 2][lm] = av.z;
    As[lk + 3][lm] = av.w;
    *(float4*)&Bs[bkr][bnc]     = bv0;
    *(float4*)&Bs[bkr][bnc + 4] = bv1;
    __syncthreads();
#pragma unroll
    for (int kk = 0; kk < 16; ++kk) {
      const float4 a4 = *(const float4*)&As[kk][ty << 2];
      const float4 b4 = *(const float4*)&Bs[kk][tx << 3];
      const float4 b5 = *(const float4*)&Bs[kk][(tx << 3) + 4];
      const float ar[4] = {a4.x, a4.y, a4.z, a4.w};
      const float br[8] = {b4.x, b4.y, b4.z, b4.w, b5.x, b5.y, b5.z, b5.w};
#pragma unroll
      for (int i = 0; i < 4; ++i)
#pragma unroll
        for (int j = 0; j < 8; ++j)
          acc[i][j] = fmaf(ar[i], br[j], acc[i][j]);
    }
  }

  float bc[8];
#pragma unroll
  for (int j = 0; j < 8; ++j) bc[j] = bias[col0 + (tx << 3) + j];

#pragma unroll
  for (int i = 0; i < 4; ++i) {
    const int r = row0 + (ty << 2) + i;
    float z[8];
#pragma unroll
    for (int j = 0; j < 8; ++j) z[j] = acc[i][j] + bc[j];
    if (EPI == EPI_QKV) {
      // y[r, c] -> q[b, c/32, n, c%32], r = b*257 + n
      const unsigned ru = (unsigned)r;
      const unsigned bb = ru / 257u;
      const unsigned nn = ru - bb * 257u;
      const int c  = col0 + (tx << 3);
      const int hh = c >> 5;
      const int d0 = c & 31;
      float* op = out + (((size_t)bb * H + hh) * N + nn) * HD + d0;
      float4 o0 = {z[0], z[1], z[2], z[3]};
      float4 o1 = {z[4], z[5], z[6], z[7]};
      *(float4*)op       = o0;
      *(float4*)(op + 4) = o1;
    } else {
      float* op = out + (size_t)r * NC + col0 + (tx << 3);
      if (EPI == EPI_GELU) {
#pragma unroll
        for (int j = 0; j < 8; ++j) z[j] = gelu_exact(z[j]);
      }
      if (EPI == EPI_RESID) {
        const float4 r0 = *(const float4*)op;
        const float4 r1 = *(const float4*)(op + 4);
        z[0] += r0.x; z[1] += r0.y; z[2] += r0.z; z[3] += r0.w;
        z[4] += r1.x; z[5] += r1.y; z[6] += r1.z; z[7] += r1.w;
      }
      float4 o0 = {z[0], z[1], z[2], z[3]};
      float4 o1 = {z[4], z[5], z[6], z[7]};
      *(float4*)op       = o0;
      *(float4*)(op + 4) = o1;
    }
  }
}

// ---------------- attention: one block per (b,h); K in LDS, V broadcast from global ----------------
// NOTE: reference applies softmax FIRST, then divides by sqrt(E)=16.
__global__ __launch_bounds__(256) void attn_kernel(
    const float* __restrict__ q, const float* __restrict__ k,
    const float* __restrict__ v, float* __restrict__ o)
{
  __shared__ __align__(16) float Ks[N * HD];  // 32,896 B
  const int bh = blockIdx.x;
  const int b  = bh >> 3;
  const int hh = bh & 7;
  const float* kp = k + (size_t)bh * N * HD;
  const float* vp = v + (size_t)bh * N * HD;
  for (int i = threadIdx.x; i < (N * HD) / 4; i += 256)
    ((float4*)Ks)[i] = ((const float4*)kp)[i];
  __syncthreads();

  for (int qi = threadIdx.x; qi < N; qi += 256) {
    float qr[HD];
    const float4* qp = (const float4*)(q + ((size_t)bh * N + qi) * HD);
#pragma unroll
    for (int d4 = 0; d4 < HD / 4; ++d4) {
      const float4 t = qp[d4];
      qr[d4 * 4 + 0] = t.x; qr[d4 * 4 + 1] = t.y;
      qr[d4 * 4 + 2] = t.z; qr[d4 * 4 + 3] = t.w;
    }
    float m = -1e30f, l = 0.0f;
    float acc[HD] = {};
    for (int j = 0; j < N; ++j) {
      const float* kr = Ks + j * HD;
      float s = 0.0f;
#pragma unroll
      for (int d = 0; d < HD; ++d) s = fmaf(qr[d], kr[d], s);
      const float mn  = fmaxf(m, s);
      const float cor = __expf(m - mn);   // m=-1e30 start -> exp(-inf)=0, safe
      const float p   = __expf(s - mn);
      l = l * cor + p;
      const float4* vr = (const float4*)(vp + (size_t)j * HD);
#pragma unroll
      for (int d4 = 0; d4 < HD / 4; ++d4) {
        const float4 vv = vr[d4];
        acc[d4 * 4 + 0] = fmaf(acc[d4 * 4 + 0], cor, p * vv.x);
        acc[d4 * 4 + 1] = fmaf(acc[d4 * 4 + 1], cor, p * vv.y);
        acc[d4 * 4 + 2] = fmaf(acc[d4 * 4 + 2], cor, p * vv.z);
        acc[d4 * 4 + 3] = fmaf(acc[d4 * 4 + 3], cor, p * vv.w);
      }
      m = mn;
    }
    const float inv = 1.0f / (16.0f * l);  // softmax denom * sqrt(E)
    float* op = o + ((size_t)b * N + qi) * E + hh * HD;
#pragma unroll
    for (int d4 = 0; d4 < HD / 4; ++d4) {
      float4 t = {acc[d4 * 4 + 0] * inv, acc[d4 * 4 + 1] * inv,
                  acc[d4 * 4 + 2] * inv, acc[d4 * 4 + 3] * inv};
      *(float4*)(op + d4 * 4) = t;
    }
  }
}

// ---------------- head: mean over N, LN, dot with head_W ----------------
__global__ __launch_bounds__(256) void head_kernel(
    const float* __restrict__ x, const float* __restrict__ g,
    const float* __restrict__ bb, const float* __restrict__ hw,
    const float* __restrict__ hbias, float* __restrict__ out)
{
  const int b = blockIdx.x;
  const int e = threadIdx.x;
  const float* xp = x + (size_t)b * N * E + e;
  float s = 0.0f;
  for (int n = 0; n < N; ++n) s += xp[(size_t)n * E];
  const float p = s / 257.0f;

  float ls = p, lq = p * p;
#pragma unroll
  for (int o = 32; o > 0; o >>= 1) { ls += __shfl_xor(ls, o); lq += __shfl_xor(lq, o); }
  __shared__ float sm[4], sv[4], sd[4];
  const int wv = e >> 6, ln = e & 63;
  if (ln == 0) { sm[wv] = ls; sv[wv] = lq; }
  __syncthreads();
  const float mean = (sm[0] + sm[1] + sm[2] + sm[3]) * (1.0f / 256.0f);
  const float var  = (sv[0] + sv[1] + sv[2] + sv[3]) * (1.0f / 256.0f) - mean * mean;
  const float y = (p - mean) * rsqrtf(var + 1e-5f) * g[e] + bb[e];
  float d = y * hw[e];
#pragma unroll
  for (int o = 32; o > 0; o >>= 1) d += __shfl_xor(d, o);
  if (ln == 0) sd[wv] = d;
  __syncthreads();
  if (e == 0) out[b] = sd[0] + sd[1] + sd[2] + sd[3] + hbias[0];
}

extern "C" void kernel_launch(void* const* d_in, const int* in_sizes, int n_in,
                              void* d_out, int out_size, void* d_ws, size_t ws_size,
                              hipStream_t stream)
{
  const int*   user = (const int*)d_in[0];
  const int*   item = (const int*)d_in[1];
  const float* utab = (const float*)d_in[2];
  const float* itab = (const float*)d_in[3];
  const float* cls  = (const float*)d_in[4];
  const float* pos  = (const float*)d_in[5];
  const float* ln1g = (const float*)d_in[6];
  const float* ln1b = (const float*)d_in[7];
  const float* Wq   = (const float*)d_in[8];
  const float* bq   = (const float*)d_in[9];
  const float* Wk   = (const float*)d_in[10];
  const float* bk   = (const float*)d_in[11];
  const float* Wv   = (const float*)d_in[12];
  const float* bv   = (const float*)d_in[13];
  const float* Wo   = (const float*)d_in[14];
  const float* bo   = (const float*)d_in[15];
  const float* ln2g = (const float*)d_in[16];
  const float* ln2b = (const float*)d_in[17];
  const float* W1   = (const float*)d_in[18];
  const float* b1   = (const float*)d_in[19];
  const float* W2   = (const float*)d_in[20];
  const float* b2   = (const float*)d_in[21];
  const float* hg   = (const float*)d_in[22];
  const float* hb   = (const float*)d_in[23];
  const float* hW   = (const float*)d_in[24];
  const float* hbias= (const float*)d_in[25];
  float* out = (float*)d_out;

  // Workspace layout (floats). Needs 6*BN*E*4 B ~= 96.4 MiB.
  // ff (4*BN*E) aliases q/k/v (+1 extra chunk) -- q,k,v are dead during FFN.
  float* x  = (float*)d_ws;
  float* h  = x  + (size_t)BN * E;
  float* qb = h  + (size_t)BN * E;
  float* kb = qb + (size_t)BN * E;
  float* vb = kb + (size_t)BN * E;
  float* ff = qb;

  embed_kernel<<<dim3(E, B), 128, 0, stream>>>(user, item, utab, itab, cls, pos, x);

  for (int L = 0; L < DEPTH; ++L) {
    ln_kernel<<<BN / 4, 256, 0, stream>>>(x, h, ln1g + L * E, ln1b + L * E);
    gemm_f32<256, 256, EPI_QKV><<<dim3(2, 257), 256, 0, stream>>>(
        h, Wq + (size_t)L * E * E, bq + L * E, qb);
    gemm_f32<256, 256, EPI_QKV><<<dim3(2, 257), 256, 0, stream>>>(
        h, Wk + (size_t)L * E * E, bk + L * E, kb);
    gemm_f32<256, 256, EPI_QKV><<<dim3(2, 257), 256, 0, stream>>>(
        h, Wv + (size_t)L * E * E, bv + L * E, vb);
    attn_kernel<<<B * H, 256, 0, stream>>>(qb, kb, vb, h);
    gemm_f32<256, 256, EPI_RESID><<<dim3(2, 257), 256, 0, stream>>>(
        h, Wo + (size_t)L * E * E, bo + L * E, x);
    ln_kernel<<<BN / 4, 256, 0, stream>>>(x, h, ln2g + L * E, ln2b + L * E);
    gemm_f32<256, 1024, EPI_GELU><<<dim3(8, 257), 256, 0, stream>>>(
        h, W1 + (size_t)L * E * FFD, b1 + L * FFD, ff);
    gemm_f32<1024, 256, EPI_RESID><<<dim3(2, 257), 256, 0, stream>>>(
        ff, W2 + (size_t)L * FFD * E, b2 + L * E, x);
  }

  head_kernel<<<B, 256, 0, stream>>>(x, hg, hb, hW, hbias, out);
}

// Round 2
// 3465.298 us; speedup vs baseline: 2.4919x; 2.4919x over previous
//
#include <hip/hip_runtime.h>
#include <hip/hip_fp16.h>
#include <math.h>

constexpr int DEPTH = 12;
constexpr int E     = 256;
constexpr int H     = 8;
constexpr int HD    = 32;
constexpr int N     = 257;
constexpr int B     = 64;
constexpr int BN    = B * N;      // 16448 = 257 * 64
constexpr int FFD   = 1024;
constexpr int UCNT  = 1000;
constexpr int Fdim  = 128;

enum { EPI_RESID = 1, EPI_GELU = 2, EPI_QKV = 3 };

typedef _Float16 f16x8 __attribute__((ext_vector_type(8)));
typedef _Float16 h2v   __attribute__((ext_vector_type(2)));
typedef float    f32x4 __attribute__((ext_vector_type(4)));

#if defined(__has_builtin)
#if __has_builtin(__builtin_amdgcn_fdot2)
#define HAS_FDOT2 1
#endif
#endif

__device__ __forceinline__ float fdot2f(h2v a, h2v b, float c) {
#ifdef HAS_FDOT2
  return __builtin_amdgcn_fdot2(a, b, c, false);
#else
  return c + (float)a[0] * (float)b[0] + (float)a[1] * (float)b[1];
#endif
}

__device__ __forceinline__ float gelu_exact(float z) {
  return 0.5f * z * (1.0f + erff(z * 0.70710678118654752440f));
}

// ---------- embed: x[b,n,e] fp32 = gathered + positions ----------
__global__ __launch_bounds__(128) void embed_kernel(
    const int* __restrict__ user, const int* __restrict__ item,
    const float* __restrict__ utab, const float* __restrict__ itab,
    const float* __restrict__ cls, const float* __restrict__ pos,
    float* __restrict__ x)
{
  const int e = blockIdx.x;
  const int b = blockIdx.y;
  const int f = threadIdx.x;
  const int uid = user[b];
  const int iid = item[b];
  const float uu = utab[((size_t)e * UCNT + uid) * Fdim + f];
  const float ii = itab[((size_t)e * UCNT + iid) * Fdim + f];
  x[((size_t)b * N + 1 + f) * E + e]        = uu + pos[(1 + f) * E + e];
  x[((size_t)b * N + 1 + Fdim + f) * E + e] = ii + pos[(1 + Fdim + f) * E + e];
  if (f == 0) x[((size_t)b * N) * E + e] = cls[e] + pos[e];
}

// ---------- weight convert+transpose: in fp32 (L,K,NC) -> out fp16 [L][NCtot][K] at col ncoff ----------
__global__ __launch_bounds__(256) void convT_kernel(
    const float* __restrict__ in, __half* __restrict__ out,
    int K, int NC, int NCtot, int ncoff)
{
  __shared__ float tile[32][33];
  const int tx = threadIdx.x, ty = threadIdx.y;  // (32,8)
  const int n0 = blockIdx.x * 32, k0 = blockIdx.y * 32;
  const float* ip = in + (size_t)blockIdx.z * K * NC;
  __half* op = out + (size_t)blockIdx.z * NCtot * K;
#pragma unroll
  for (int r = 0; r < 4; ++r) {
    const int kk = ty + r * 8;
    tile[kk][tx] = ip[(size_t)(k0 + kk) * NC + n0 + tx];
  }
  __syncthreads();
#pragma unroll
  for (int r = 0; r < 4; ++r) {
    const int nn = ty + r * 8;
    op[(size_t)(ncoff + n0 + nn) * K + k0 + tx] = __float2half(tile[tx][nn]);
  }
}

// ---------- layernorm: wave per row; x fp32 in, h fp16 out ----------
__global__ __launch_bounds__(256) void ln_kernel(
    const float* __restrict__ x, __half* __restrict__ y,
    const float* __restrict__ g, const float* __restrict__ b)
{
  const int wave = threadIdx.x >> 6, lane = threadIdx.x & 63;
  const int row  = blockIdx.x * 4 + wave;
  const float4 v = *(const float4*)(x + (size_t)row * E + lane * 4);
  float s = v.x + v.y + v.z + v.w;
  float q = v.x * v.x + v.y * v.y + v.z * v.z + v.w * v.w;
#pragma unroll
  for (int o = 32; o > 0; o >>= 1) { s += __shfl_xor(s, o); q += __shfl_xor(q, o); }
  const float mean = s * (1.0f / 256.0f);
  const float var  = q * (1.0f / 256.0f) - mean * mean;
  const float rstd = rsqrtf(var + 1e-5f);
  const float4 gg = *(const float4*)(g + lane * 4);
  const float4 bb = *(const float4*)(b + lane * 4);
  __half2 h0 = __floats2half2_rn((v.x - mean) * rstd * gg.x + bb.x,
                                 (v.y - mean) * rstd * gg.y + bb.y);
  __half2 h1 = __floats2half2_rn((v.z - mean) * rstd * gg.z + bb.z,
                                 (v.w - mean) * rstd * gg.w + bb.w);
  __half2* yp = (__half2*)(y + (size_t)row * E + lane * 4);
  yp[0] = h0; yp[1] = h1;
}

// ---------- fp16 MFMA GEMM: C(BN x NCOUT) = A(BN x K) @ Wt^T + bias, fused epilogue ----------
// A fp16 row-major (lda=K); Wt fp16 [NCOUT][K] (K-major). Block: 256 thr, tile 64x128.
// 4 waves, each 32x64 (2x4 mfma 16x16x32 tiles). LDS-transpose epilogue for coalesced stores.
template<int K, int NCOUT, int EPI>
__global__ __launch_bounds__(256) void gemm_f16(
    const __half* __restrict__ A, const __half* __restrict__ Wt,
    const float* __restrict__ b0, const float* __restrict__ b1,
    const float* __restrict__ b2, void* __restrict__ outp)
{
  __shared__ __align__(16) char smem[64 * 132 * 4];   // 33,792 B
  __half (*As)[40] = (__half(*)[40])smem;             // 64 x 40 fp16 = 5120 B
  __half (*Ws)[40] = (__half(*)[40])(smem + 5120);    // 128 x 40 fp16 = 10240 B
  float* Cs = (float*)smem;                           // 64 x 132 f32

  const int t    = threadIdx.x;
  const int row0 = blockIdx.y * 64;
  const int col0 = blockIdx.x * 128;
  const int wave = t >> 6, lane = t & 63;
  const int wm = (wave >> 1) * 32;
  const int wn = (wave & 1) * 64;
  const int lm = lane & 15, lq = lane >> 4;

  const int ar = t >> 2, ak = (t & 3) * 8;   // A staging: row, k-seg (8 halves)
  const int wr = t >> 1, wk = (t & 1) * 16;  // W staging: n-row, k-seg (16 halves)

  f32x4 acc[2][4];
#pragma unroll
  for (int i = 0; i < 2; ++i)
#pragma unroll
    for (int j = 0; j < 4; ++j) acc[i][j] = (f32x4){0.f, 0.f, 0.f, 0.f};

  for (int k0 = 0; k0 < K; k0 += 32) {
    const float4 av  = *(const float4*)(A  + (size_t)(row0 + ar) * K + k0 + ak);
    const float4 wv0 = *(const float4*)(Wt + (size_t)(col0 + wr) * K + k0 + wk);
    const float4 wv1 = *(const float4*)(Wt + (size_t)(col0 + wr) * K + k0 + wk + 8);
    __syncthreads();
    *(float4*)&As[ar][ak]      = av;
    *(float4*)&Ws[wr][wk]      = wv0;
    *(float4*)&Ws[wr][wk + 8]  = wv1;
    __syncthreads();
    f16x8 af[2], bf[4];
#pragma unroll
    for (int mt = 0; mt < 2; ++mt)
      af[mt] = *(const f16x8*)&As[wm + mt * 16 + lm][lq * 8];
#pragma unroll
    for (int nt = 0; nt < 4; ++nt)
      bf[nt] = *(const f16x8*)&Ws[wn + nt * 16 + lm][lq * 8];
#pragma unroll
    for (int mt = 0; mt < 2; ++mt)
#pragma unroll
      for (int nt = 0; nt < 4; ++nt)
        acc[mt][nt] = __builtin_amdgcn_mfma_f32_16x16x32_f16(af[mt], bf[nt], acc[mt][nt], 0, 0, 0);
  }

  __syncthreads();
  // scatter acc into Cs (C/D layout: n = lane&15, m = lq*4 + reg)
#pragma unroll
  for (int mt = 0; mt < 2; ++mt)
#pragma unroll
    for (int nt = 0; nt < 4; ++nt) {
      const int cc = wn + nt * 16 + lm;
#pragma unroll
      for (int r = 0; r < 4; ++r) {
        const int rr = wm + mt * 16 + lq * 4 + r;
        Cs[rr * 132 + cc] = acc[mt][nt][r];
      }
    }
  __syncthreads();

  // coalesced readback + epilogue: 4 iters x 8 elems/thread
#pragma unroll
  for (int i = 0; i < 4; ++i) {
    const int flat = i * 2048 + t * 8;
    const int row = flat >> 7, col = flat & 127;
    const int token = row0 + row;
    const int cg = col0 + col;
    float v[8];
    *(float4*)&v[0] = *(const float4*)&Cs[row * 132 + col];
    *(float4*)&v[4] = *(const float4*)&Cs[row * 132 + col + 4];

    if (EPI == EPI_QKV) {
      const int tsel = cg >> 8;
      const int rc   = cg & 255;
      const float* bp = (tsel == 0) ? b0 : (tsel == 1 ? b1 : b2);
#pragma unroll
      for (int j = 0; j < 8; ++j) v[j] += bp[rc + j];
      const unsigned tu = (unsigned)token;
      const unsigned bb = tu / 257u;
      const unsigned nn = tu - bb * 257u;
      const int hh = rc >> 5, d0 = rc & 31;
      __half* dst = (__half*)outp + (size_t)tsel * (BN * 256)
                  + (((size_t)bb * H + hh) * N + nn) * HD + d0;
      __align__(16) __half hv[8];
#pragma unroll
      for (int j = 0; j < 8; ++j) hv[j] = __float2half(v[j]);
      *(float4*)dst = *(const float4*)hv;
    } else if (EPI == EPI_GELU) {
#pragma unroll
      for (int j = 0; j < 8; ++j) v[j] = gelu_exact(v[j] + b0[cg + j]);
      __align__(16) __half hv[8];
#pragma unroll
      for (int j = 0; j < 8; ++j) hv[j] = __float2half(v[j]);
      *(float4*)((__half*)outp + (size_t)token * NCOUT + cg) = *(const float4*)hv;
    } else {  // EPI_RESID: out fp32 += gemm + bias
      float* xo = (float*)outp + (size_t)token * 256 + cg;
      const float4 x0 = *(const float4*)xo;
      const float4 x1 = *(const float4*)(xo + 4);
      v[0] += b0[cg + 0] + x0.x; v[1] += b0[cg + 1] + x0.y;
      v[2] += b0[cg + 2] + x0.z; v[3] += b0[cg + 3] + x0.w;
      v[4] += b0[cg + 4] + x1.x; v[5] += b0[cg + 5] + x1.y;
      v[6] += b0[cg + 6] + x1.z; v[7] += b0[cg + 7] + x1.w;
      *(float4*)xo       = *(const float4*)&v[0];
      *(float4*)(xo + 4) = *(const float4*)&v[4];
    }
  }
}

// ---------- attention: block per (b,h), 320 thr, thread per q-row; K/V fp16 in LDS ----------
// LDS reads are wave-uniform (same key j) -> broadcast, conflict-free.
// Reference: softmax first, then / sqrt(E)=16.
__global__ __launch_bounds__(320) void attn_f16(
    const __half* __restrict__ q, const __half* __restrict__ k,
    const __half* __restrict__ v, __half* __restrict__ o)
{
  __shared__ __align__(16) __half Ks[N][HD];
  __shared__ __align__(16) __half Vs[N][HD];
  const int bh = blockIdx.x;
  const int bb = bh >> 3, hh = bh & 7;
  const float4* kp = (const float4*)(k + (size_t)bh * N * HD);
  const float4* vp = (const float4*)(v + (size_t)bh * N * HD);
  for (int i = threadIdx.x; i < N * HD / 8; i += 320) {
    ((float4*)Ks)[i] = kp[i];
    ((float4*)Vs)[i] = vp[i];
  }
  __syncthreads();

  const int qi = threadIdx.x;
  if (qi < N) {
    h2v qr[16];
    const float4* qp = (const float4*)(q + ((size_t)bh * N + qi) * HD);
    *(float4*)&qr[0]  = qp[0];
    *(float4*)&qr[4]  = qp[1];
    *(float4*)&qr[8]  = qp[2];
    *(float4*)&qr[12] = qp[3];
    float m = -1e30f, l = 0.0f;
    float acc[HD] = {};
    for (int j = 0; j < N; ++j) {
      const h2v* kr = (const h2v*)Ks[j];
      float s = 0.0f;
#pragma unroll
      for (int i2 = 0; i2 < 16; ++i2) s = fdot2f(qr[i2], kr[i2], s);
      const float mn  = fmaxf(m, s);
      const float cor = __expf(m - mn);
      const float p   = __expf(s - mn);
      l = l * cor + p;
      const __half2* vr = (const __half2*)Vs[j];
#pragma unroll
      for (int i2 = 0; i2 < 16; ++i2) {
        const float2 vf = __half22float2(vr[i2]);
        acc[2 * i2]     = fmaf(acc[2 * i2],     cor, p * vf.x);
        acc[2 * i2 + 1] = fmaf(acc[2 * i2 + 1], cor, p * vf.y);
      }
      m = mn;
    }
    const float inv = 1.0f / (16.0f * l);
    __align__(16) __half2 ov[16];
#pragma unroll
    for (int i2 = 0; i2 < 16; ++i2)
      ov[i2] = __floats2half2_rn(acc[2 * i2] * inv, acc[2 * i2 + 1] * inv);
    float4* op = (float4*)(o + ((size_t)bb * N + qi) * E + hh * HD);
#pragma unroll
    for (int i2 = 0; i2 < 4; ++i2) op[i2] = ((const float4*)ov)[i2];
  }
}

// ---------- head: mean over N, LN, dot ----------
__global__ __launch_bounds__(256) void head_kernel(
    const float* __restrict__ x, const float* __restrict__ g,
    const float* __restrict__ bb, const float* __restrict__ hw,
    const float* __restrict__ hbias, float* __restrict__ out)
{
  const int b = blockIdx.x;
  const int e = threadIdx.x;
  const float* xp = x + (size_t)b * N * E + e;
  float s = 0.0f;
  for (int n = 0; n < N; ++n) s += xp[(size_t)n * E];
  const float p = s / 257.0f;

  float ls = p, lq = p * p;
#pragma unroll
  for (int o = 32; o > 0; o >>= 1) { ls += __shfl_xor(ls, o); lq += __shfl_xor(lq, o); }
  __shared__ float sm[4], sv[4], sd[4];
  const int wv = e >> 6, ln = e & 63;
  if (ln == 0) { sm[wv] = ls; sv[wv] = lq; }
  __syncthreads();
  const float mean = (sm[0] + sm[1] + sm[2] + sm[3]) * (1.0f / 256.0f);
  const float var  = (sv[0] + sv[1] + sv[2] + sv[3]) * (1.0f / 256.0f) - mean * mean;
  const float y = (p - mean) * rsqrtf(var + 1e-5f) * g[e] + bb[e];
  float d = y * hw[e];
#pragma unroll
  for (int o = 32; o > 0; o >>= 1) d += __shfl_xor(d, o);
  if (ln == 0) sd[wv] = d;
  __syncthreads();
  if (e == 0) out[b] = sd[0] + sd[1] + sd[2] + sd[3] + hbias[0];
}

extern "C" void kernel_launch(void* const* d_in, const int* in_sizes, int n_in,
                              void* d_out, int out_size, void* d_ws, size_t ws_size,
                              hipStream_t stream)
{
  const int*   user = (const int*)d_in[0];
  const int*   item = (const int*)d_in[1];
  const float* utab = (const float*)d_in[2];
  const float* itab = (const float*)d_in[3];
  const float* cls  = (const float*)d_in[4];
  const float* pos  = (const float*)d_in[5];
  const float* ln1g = (const float*)d_in[6];
  const float* ln1b = (const float*)d_in[7];
  const float* Wq   = (const float*)d_in[8];
  const float* bq   = (const float*)d_in[9];
  const float* Wk   = (const float*)d_in[10];
  const float* bk   = (const float*)d_in[11];
  const float* Wv   = (const float*)d_in[12];
  const float* bv   = (const float*)d_in[13];
  const float* Wo   = (const float*)d_in[14];
  const float* bo   = (const float*)d_in[15];
  const float* ln2g = (const float*)d_in[16];
  const float* ln2b = (const float*)d_in[17];
  const float* W1   = (const float*)d_in[18];
  const float* b1   = (const float*)d_in[19];
  const float* W2   = (const float*)d_in[20];
  const float* b2   = (const float*)d_in[21];
  const float* hg   = (const float*)d_in[22];
  const float* hb   = (const float*)d_in[23];
  const float* hW   = (const float*)d_in[24];
  const float* hbias= (const float*)d_in[25];
  float* out = (float*)d_out;

  // Workspace layout (77.8 MB total; round-1 used 101 MB OK):
  // x fp32 | h fp16 | ffqkv fp16 (ff 64x..x1024, aliases q/k/v) | Wqkvt | Wot | W1t | W2t
  float*  x  = (float*)d_ws;
  __half* h  = (__half*)(x + (size_t)BN * E);
  __half* fq = h + (size_t)BN * E;                   // q | k | v  (each BN*256), ff spans all
  __half* Wqkvt = fq + (size_t)BN * FFD;             // 12 x 768 x 256
  __half* Wot   = Wqkvt + (size_t)DEPTH * 768 * 256; // 12 x 256 x 256
  __half* W1t   = Wot   + (size_t)DEPTH * 256 * 256; // 12 x 1024 x 256
  __half* W2t   = W1t   + (size_t)DEPTH * 1024 * 256;// 12 x 256 x 1024
  __half* qb = fq;
  __half* kb = fq + (size_t)BN * 256;
  __half* vb = fq + (size_t)2 * BN * 256;

  // weight convert+transpose (per-call; inputs re-poisoned each launch)
  convT_kernel<<<dim3(8, 8, DEPTH),  dim3(32, 8), 0, stream>>>(Wq, Wqkvt, 256, 256, 768, 0);
  convT_kernel<<<dim3(8, 8, DEPTH),  dim3(32, 8), 0, stream>>>(Wk, Wqkvt, 256, 256, 768, 256);
  convT_kernel<<<dim3(8, 8, DEPTH),  dim3(32, 8), 0, stream>>>(Wv, Wqkvt, 256, 256, 768, 512);
  convT_kernel<<<dim3(8, 8, DEPTH),  dim3(32, 8), 0, stream>>>(Wo, Wot, 256, 256, 256, 0);
  convT_kernel<<<dim3(32, 8, DEPTH), dim3(32, 8), 0, stream>>>(W1, W1t, 256, 1024, 1024, 0);
  convT_kernel<<<dim3(8, 32, DEPTH), dim3(32, 8), 0, stream>>>(W2, W2t, 1024, 256, 256, 0);

  embed_kernel<<<dim3(E, B), 128, 0, stream>>>(user, item, utab, itab, cls, pos, x);

  for (int L = 0; L < DEPTH; ++L) {
    ln_kernel<<<BN / 4, 256, 0, stream>>>(x, h, ln1g + L * E, ln1b + L * E);
    gemm_f16<256, 768, EPI_QKV><<<dim3(6, 257), 256, 0, stream>>>(
        h, Wqkvt + (size_t)L * 768 * 256, bq + L * E, bk + L * E, bv + L * E, fq);
    attn_f16<<<B * H, 320, 0, stream>>>(qb, kb, vb, h);
    gemm_f16<256, 256, EPI_RESID><<<dim3(2, 257), 256, 0, stream>>>(
        h, Wot + (size_t)L * 256 * 256, bo + L * E, bo + L * E, bo + L * E, x);
    ln_kernel<<<BN / 4, 256, 0, stream>>>(x, h, ln2g + L * E, ln2b + L * E);
    gemm_f16<256, 1024, EPI_GELU><<<dim3(8, 257), 256, 0, stream>>>(
        h, W1t + (size_t)L * 1024 * 256, b1 + L * FFD, b1 + L * FFD, b1 + L * FFD, fq);
    gemm_f16<1024, 256, EPI_RESID><<<dim3(2, 257), 256, 0, stream>>>(
        fq, W2t + (size_t)L * 256 * 1024, b2 + L * E, b2 + L * E, b2 + L * E, x);
  }

  head_kernel<<<B, 256, 0, stream>>>(x, hg, hb, hW, hbias, out);
}

// Round 4
// 1968.886 us; speedup vs baseline: 4.3858x; 1.7600x over previous
//
#include <hip/hip_runtime.h>
#include <hip/hip_fp16.h>
#include <math.h>

constexpr int DEPTH = 12;
constexpr int E     = 256;
constexpr int H     = 8;
constexpr int HD    = 32;
constexpr int N     = 257;
constexpr int B     = 64;
constexpr int BN    = B * N;      // 16448 = 257 * 64
constexpr int FFD   = 1024;
constexpr int UCNT  = 1000;
constexpr int Fdim  = 128;

enum { EPI_RESID = 1, EPI_GELU = 2, EPI_QKV = 3 };

typedef _Float16 f16x8 __attribute__((ext_vector_type(8)));
typedef _Float16 f16x4 __attribute__((ext_vector_type(4)));
typedef float    f32x4 __attribute__((ext_vector_type(4)));

__device__ __forceinline__ float gelu_exact(float z) {
  return 0.5f * z * (1.0f + erff(z * 0.70710678118654752440f));
}

// ---------- embed: x[b,n,e] fp32 = gathered + positions ----------
__global__ __launch_bounds__(128) void embed_kernel(
    const int* __restrict__ user, const int* __restrict__ item,
    const float* __restrict__ utab, const float* __restrict__ itab,
    const float* __restrict__ cls, const float* __restrict__ pos,
    float* __restrict__ x)
{
  const int e = blockIdx.x;
  const int b = blockIdx.y;
  const int f = threadIdx.x;
  const int uid = user[b];
  const int iid = item[b];
  const float uu = utab[((size_t)e * UCNT + uid) * Fdim + f];
  const float ii = itab[((size_t)e * UCNT + iid) * Fdim + f];
  x[((size_t)b * N + 1 + f) * E + e]        = uu + pos[(1 + f) * E + e];
  x[((size_t)b * N + 1 + Fdim + f) * E + e] = ii + pos[(1 + Fdim + f) * E + e];
  if (f == 0) x[((size_t)b * N) * E + e] = cls[e] + pos[e];
}

// ---------- weight convert+transpose: fp32 (L,K,NC) -> fp16 [L][NCtot][K] at col ncoff ----------
__global__ __launch_bounds__(256) void convT_kernel(
    const float* __restrict__ in, __half* __restrict__ out,
    int K, int NC, int NCtot, int ncoff)
{
  __shared__ float tile[32][33];
  const int tx = threadIdx.x, ty = threadIdx.y;  // (32,8)
  const int n0 = blockIdx.x * 32, k0 = blockIdx.y * 32;
  const float* ip = in + (size_t)blockIdx.z * K * NC;
  __half* op = out + (size_t)blockIdx.z * NCtot * K;
#pragma unroll
  for (int r = 0; r < 4; ++r) {
    const int kk = ty + r * 8;
    tile[kk][tx] = ip[(size_t)(k0 + kk) * NC + n0 + tx];
  }
  __syncthreads();
#pragma unroll
  for (int r = 0; r < 4; ++r) {
    const int nn = ty + r * 8;
    op[(size_t)(ncoff + n0 + nn) * K + k0 + tx] = __float2half(tile[tx][nn]);
  }
}

// ---------- layernorm: wave per row; x fp32 in, h fp16 out ----------
__global__ __launch_bounds__(256) void ln_kernel(
    const float* __restrict__ x, __half* __restrict__ y,
    const float* __restrict__ g, const float* __restrict__ b)
{
  const int wave = threadIdx.x >> 6, lane = threadIdx.x & 63;
  const int row  = blockIdx.x * 4 + wave;
  const float4 v = *(const float4*)(x + (size_t)row * E + lane * 4);
  float s = v.x + v.y + v.z + v.w;
  float q = v.x * v.x + v.y * v.y + v.z * v.z + v.w * v.w;
#pragma unroll
  for (int o = 32; o > 0; o >>= 1) { s += __shfl_xor(s, o); q += __shfl_xor(q, o); }
  const float mean = s * (1.0f / 256.0f);
  const float var  = q * (1.0f / 256.0f) - mean * mean;
  const float rstd = rsqrtf(var + 1e-5f);
  const float4 gg = *(const float4*)(g + lane * 4);
  const float4 bb = *(const float4*)(b + lane * 4);
  __half2 h0 = __floats2half2_rn((v.x - mean) * rstd * gg.x + bb.x,
                                 (v.y - mean) * rstd * gg.y + bb.y);
  __half2 h1 = __floats2half2_rn((v.z - mean) * rstd * gg.z + bb.z,
                                 (v.w - mean) * rstd * gg.w + bb.w);
  __half2* yp = (__half2*)(y + (size_t)row * E + lane * 4);
  yp[0] = h0; yp[1] = h1;
}

// ---------- fp16 MFMA GEMM: C(BN x NCOUT) = A(BN x K) @ Wt^T + bias, fused epilogue ----------
template<int K, int NCOUT, int EPI>
__global__ __launch_bounds__(256) void gemm_f16(
    const __half* __restrict__ A, const __half* __restrict__ Wt,
    const float* __restrict__ b0, const float* __restrict__ b1,
    const float* __restrict__ b2, void* __restrict__ outp)
{
  __shared__ __align__(16) char smem[64 * 132 * 4];   // 33,792 B
  __half (*As)[40] = (__half(*)[40])smem;             // 64 x 40 fp16
  __half (*Ws)[40] = (__half(*)[40])(smem + 5120);    // 128 x 40 fp16
  float* Cs = (float*)smem;                           // 64 x 132 f32

  const int t    = threadIdx.x;
  const int row0 = blockIdx.y * 64;
  const int col0 = blockIdx.x * 128;
  const int wave = t >> 6, lane = t & 63;
  const int wm = (wave >> 1) * 32;
  const int wn = (wave & 1) * 64;
  const int lm = lane & 15, lq = lane >> 4;

  const int ar = t >> 2, ak = (t & 3) * 8;
  const int wr = t >> 1, wk = (t & 1) * 16;

  f32x4 acc[2][4];
#pragma unroll
  for (int i = 0; i < 2; ++i)
#pragma unroll
    for (int j = 0; j < 4; ++j) acc[i][j] = (f32x4){0.f, 0.f, 0.f, 0.f};

  for (int k0 = 0; k0 < K; k0 += 32) {
    const float4 av  = *(const float4*)(A  + (size_t)(row0 + ar) * K + k0 + ak);
    const float4 wv0 = *(const float4*)(Wt + (size_t)(col0 + wr) * K + k0 + wk);
    const float4 wv1 = *(const float4*)(Wt + (size_t)(col0 + wr) * K + k0 + wk + 8);
    __syncthreads();
    *(float4*)&As[ar][ak]      = av;
    *(float4*)&Ws[wr][wk]      = wv0;
    *(float4*)&Ws[wr][wk + 8]  = wv1;
    __syncthreads();
    f16x8 af[2], bf[4];
#pragma unroll
    for (int mt = 0; mt < 2; ++mt)
      af[mt] = *(const f16x8*)&As[wm + mt * 16 + lm][lq * 8];
#pragma unroll
    for (int nt = 0; nt < 4; ++nt)
      bf[nt] = *(const f16x8*)&Ws[wn + nt * 16 + lm][lq * 8];
#pragma unroll
    for (int mt = 0; mt < 2; ++mt)
#pragma unroll
      for (int nt = 0; nt < 4; ++nt)
        acc[mt][nt] = __builtin_amdgcn_mfma_f32_16x16x32_f16(af[mt], bf[nt], acc[mt][nt], 0, 0, 0);
  }

  __syncthreads();
#pragma unroll
  for (int mt = 0; mt < 2; ++mt)
#pragma unroll
    for (int nt = 0; nt < 4; ++nt) {
      const int cc = wn + nt * 16 + lm;
#pragma unroll
      for (int r = 0; r < 4; ++r) {
        const int rr = wm + mt * 16 + lq * 4 + r;
        Cs[rr * 132 + cc] = acc[mt][nt][r];
      }
    }
  __syncthreads();

#pragma unroll
  for (int i = 0; i < 4; ++i) {
    const int flat = i * 2048 + t * 8;
    const int row = flat >> 7, col = flat & 127;
    const int token = row0 + row;
    const int cg = col0 + col;
    float v[8];
    *(float4*)&v[0] = *(const float4*)&Cs[row * 132 + col];
    *(float4*)&v[4] = *(const float4*)&Cs[row * 132 + col + 4];

    if (EPI == EPI_QKV) {
      const int tsel = cg >> 8;
      const int rc   = cg & 255;
      const float* bp = (tsel == 0) ? b0 : (tsel == 1 ? b1 : b2);
#pragma unroll
      for (int j = 0; j < 8; ++j) v[j] += bp[rc + j];
      const unsigned tu = (unsigned)token;
      const unsigned bb = tu / 257u;
      const unsigned nn = tu - bb * 257u;
      const int hh = rc >> 5, d0 = rc & 31;
      __half* dst = (__half*)outp + (size_t)tsel * (BN * 256)
                  + (((size_t)bb * H + hh) * N + nn) * HD + d0;
      __align__(16) __half hv[8];
#pragma unroll
      for (int j = 0; j < 8; ++j) hv[j] = __float2half(v[j]);
      *(float4*)dst = *(const float4*)hv;
    } else if (EPI == EPI_GELU) {
#pragma unroll
      for (int j = 0; j < 8; ++j) v[j] = gelu_exact(v[j] + b0[cg + j]);
      __align__(16) __half hv[8];
#pragma unroll
      for (int j = 0; j < 8; ++j) hv[j] = __float2half(v[j]);
      *(float4*)((__half*)outp + (size_t)token * NCOUT + cg) = *(const float4*)hv;
    } else {  // EPI_RESID
      float* xo = (float*)outp + (size_t)token * 256 + cg;
      const float4 x0 = *(const float4*)xo;
      const float4 x1 = *(const float4*)(xo + 4);
      v[0] += b0[cg + 0] + x0.x; v[1] += b0[cg + 1] + x0.y;
      v[2] += b0[cg + 2] + x0.z; v[3] += b0[cg + 3] + x0.w;
      v[4] += b0[cg + 4] + x1.x; v[5] += b0[cg + 5] + x1.y;
      v[6] += b0[cg + 6] + x1.z; v[7] += b0[cg + 7] + x1.w;
      *(float4*)xo       = *(const float4*)&v[0];
      *(float4*)(xo + 4) = *(const float4*)&v[4];
    }
  }
}

// ---------- MFMA flash attention ----------
// Block = 256 thr (4 waves), grid = (512 bh, 2 q-chunks).
// S^T = K·Q^T via mfma_16x16x32 (C layout: col=q=lane&15, row=key=quad*4+r)
// -> softmax stats per-lane scalars; P^T C-layout == B-operand layout of
// mfma_f32_16x16x16f16 -> PV with zero cross-lane movement: O^T += V^T x P^T.
// O^T stored DIRECTLY from registers (d = quad*4+r contiguous -> f16x4 stores).
// Keys padded to 272 (zeros + -3e38 mask); q rows clamped on load, guarded on store.
// Reference semantics: softmax on raw energy, THEN divide by sqrt(E)=16.
__global__ __launch_bounds__(256) void attn_mfma(
    const __half* __restrict__ q, const __half* __restrict__ k,
    const __half* __restrict__ v, __half* __restrict__ o)
{
  __shared__ __align__(16) __half Ks[272][40];   // [key][hd]
  __shared__ __align__(16) __half Vt[32][280];   // [hd][key]

  const int bh = blockIdx.x;
  const int chunk = blockIdx.y;
  const int bb = bh >> 3, hh = bh & 7;
  const int t = threadIdx.x;
  const int wave = t >> 6, lane = t & 63;
  const int lm = lane & 15, lq = lane >> 4;

  const __half* kg = k + (size_t)bh * N * HD;
  const __half* vg = v + (size_t)bh * N * HD;

  const f16x8 zero8 = {0, 0, 0, 0, 0, 0, 0, 0};
  for (int i = t; i < 272 * 4; i += 256) {
    const int n = i >> 2, c8 = (i & 3) * 8;
    f16x8 kv = zero8, vv = zero8;
    if (n < N) {
      kv = *(const f16x8*)(kg + (size_t)n * HD + c8);
      vv = *(const f16x8*)(vg + (size_t)n * HD + c8);
    }
    *(f16x8*)&Ks[n][c8] = kv;
#pragma unroll
    for (int j = 0; j < 8; ++j) Vt[c8 + j][n] = vv[j];
  }
  __syncthreads();

  const int ntiles = chunk ? 8 : 9;
  const int tbase  = chunk ? 9 : 0;
  for (int ti = wave; ti < ntiles; ti += 4) {
    const int q0 = (tbase + ti) * 16;
    const int qg = q0 + lm;
    const int qrow = (qg < N) ? qg : (N - 1);   // clamp: no OOB; result discarded at store
    const f16x8 bq = *(const f16x8*)(q + ((size_t)bh * N + qrow) * HD + lq * 8);
    f32x4 Ot0 = {0.f, 0.f, 0.f, 0.f}, Ot1 = {0.f, 0.f, 0.f, 0.f};
    float mm = -3.0e38f, ll = 0.0f;

    for (int kt = 0; kt < 17; ++kt) {
      const int k0 = kt * 16;
      const f16x8 ak = *(const f16x8*)&Ks[k0 + lm][lq * 8];  // A: m=key, k=hd
      f32x4 s = __builtin_amdgcn_mfma_f32_16x16x32_f16(ak, bq, (f32x4){0.f, 0.f, 0.f, 0.f}, 0, 0, 0);
      if (k0 == 256) {  // mask padded keys (key = 256 + lq*4 + r; only key 256 valid)
        if (lq != 0) s[0] = -3.0e38f;
        s[1] = -3.0e38f; s[2] = -3.0e38f; s[3] = -3.0e38f;
      }
      float tm = fmaxf(fmaxf(s[0], s[1]), fmaxf(s[2], s[3]));
      tm = fmaxf(tm, __shfl_xor(tm, 16));
      tm = fmaxf(tm, __shfl_xor(tm, 32));
      const float mn    = fmaxf(mm, tm);
      const float alpha = __expf(mm - mn);
      const float p0 = __expf(s[0] - mn);
      const float p1 = __expf(s[1] - mn);
      const float p2 = __expf(s[2] - mn);
      const float p3 = __expf(s[3] - mn);
      float ts = p0 + p1 + p2 + p3;
      ts += __shfl_xor(ts, 16);
      ts += __shfl_xor(ts, 32);
      ll = ll * alpha + ts;
      Ot0 *= alpha;
      Ot1 *= alpha;
      const f16x4 pb = {(_Float16)p0, (_Float16)p1, (_Float16)p2, (_Float16)p3};
      const f16x4 av0 = *(const f16x4*)&Vt[lm][k0 + lq * 4];       // A: m=d(0..15), k=key
      const f16x4 av1 = *(const f16x4*)&Vt[16 + lm][k0 + lq * 4];  // A: m=d(16..31)
      Ot0 = __builtin_amdgcn_mfma_f32_16x16x16f16(av0, pb, Ot0, 0, 0, 0);
      Ot1 = __builtin_amdgcn_mfma_f32_16x16x16f16(av1, pb, Ot1, 0, 0, 0);
      mm = mn;
    }

    // direct register store: lane (lm,lq) holds q=q0+lm, d = lq*4..+3 and 16+lq*4..+3
    const float inv = 1.0f / (16.0f * ll);  // full row-sum (quad-reduced each tile)
    if (qg < N) {
      __half* op = o + ((size_t)bb * N + qg) * E + hh * HD + lq * 4;
      __half2* p0 = (__half2*)op;
      p0[0] = __floats2half2_rn(Ot0[0] * inv, Ot0[1] * inv);
      p0[1] = __floats2half2_rn(Ot0[2] * inv, Ot0[3] * inv);
      __half2* p1 = (__half2*)(op + 16);
      p1[0] = __floats2half2_rn(Ot1[0] * inv, Ot1[1] * inv);
      p1[1] = __floats2half2_rn(Ot1[2] * inv, Ot1[3] * inv);
    }
  }
}

// ---------- head: mean over N, LN, dot ----------
__global__ __launch_bounds__(256) void head_kernel(
    const float* __restrict__ x, const float* __restrict__ g,
    const float* __restrict__ bb, const float* __restrict__ hw,
    const float* __restrict__ hbias, float* __restrict__ out)
{
  const int b = blockIdx.x;
  const int e = threadIdx.x;
  const float* xp = x + (size_t)b * N * E + e;
  float s = 0.0f;
  for (int n = 0; n < N; ++n) s += xp[(size_t)n * E];
  const float p = s / 257.0f;

  float ls = p, lq = p * p;
#pragma unroll
  for (int o = 32; o > 0; o >>= 1) { ls += __shfl_xor(ls, o); lq += __shfl_xor(lq, o); }
  __shared__ float sm[4], sv[4], sd[4];
  const int wv = e >> 6, ln = e & 63;
  if (ln == 0) { sm[wv] = ls; sv[wv] = lq; }
  __syncthreads();
  const float mean = (sm[0] + sm[1] + sm[2] + sm[3]) * (1.0f / 256.0f);
  const float var  = (sv[0] + sv[1] + sv[2] + sv[3]) * (1.0f / 256.0f) - mean * mean;
  const float y = (p - mean) * rsqrtf(var + 1e-5f) * g[e] + bb[e];
  float d = y * hw[e];
#pragma unroll
  for (int o = 32; o > 0; o >>= 1) d += __shfl_xor(d, o);
  if (ln == 0) sd[wv] = d;
  __syncthreads();
  if (e == 0) out[b] = sd[0] + sd[1] + sd[2] + sd[3] + hbias[0];
}

extern "C" void kernel_launch(void* const* d_in, const int* in_sizes, int n_in,
                              void* d_out, int out_size, void* d_ws, size_t ws_size,
                              hipStream_t stream)
{
  const int*   user = (const int*)d_in[0];
  const int*   item = (const int*)d_in[1];
  const float* utab = (const float*)d_in[2];
  const float* itab = (const float*)d_in[3];
  const float* cls  = (const float*)d_in[4];
  const float* pos  = (const float*)d_in[5];
  const float* ln1g = (const float*)d_in[6];
  const float* ln1b = (const float*)d_in[7];
  const float* Wq   = (const float*)d_in[8];
  const float* bq   = (const float*)d_in[9];
  const float* Wk   = (const float*)d_in[10];
  const float* bk   = (const float*)d_in[11];
  const float* Wv   = (const float*)d_in[12];
  const float* bv   = (const float*)d_in[13];
  const float* Wo   = (const float*)d_in[14];
  const float* bo   = (const float*)d_in[15];
  const float* ln2g = (const float*)d_in[16];
  const float* ln2b = (const float*)d_in[17];
  const float* W1   = (const float*)d_in[18];
  const float* b1   = (const float*)d_in[19];
  const float* W2   = (const float*)d_in[20];
  const float* b2   = (const float*)d_in[21];
  const float* hg   = (const float*)d_in[22];
  const float* hb   = (const float*)d_in[23];
  const float* hW   = (const float*)d_in[24];
  const float* hbias= (const float*)d_in[25];
  float* out = (float*)d_out;

  float*  x  = (float*)d_ws;
  __half* h  = (__half*)(x + (size_t)BN * E);
  __half* fq = h + (size_t)BN * E;                   // q | k | v (each BN*256); ff spans all
  __half* Wqkvt = fq + (size_t)BN * FFD;             // 12 x 768 x 256
  __half* Wot   = Wqkvt + (size_t)DEPTH * 768 * 256; // 12 x 256 x 256
  __half* W1t   = Wot   + (size_t)DEPTH * 256 * 256; // 12 x 1024 x 256
  __half* W2t   = W1t   + (size_t)DEPTH * 1024 * 256;// 12 x 256 x 1024
  __half* qb = fq;
  __half* kb = fq + (size_t)BN * 256;
  __half* vb = fq + (size_t)2 * BN * 256;

  convT_kernel<<<dim3(8, 8, DEPTH),  dim3(32, 8), 0, stream>>>(Wq, Wqkvt, 256, 256, 768, 0);
  convT_kernel<<<dim3(8, 8, DEPTH),  dim3(32, 8), 0, stream>>>(Wk, Wqkvt, 256, 256, 768, 256);
  convT_kernel<<<dim3(8, 8, DEPTH),  dim3(32, 8), 0, stream>>>(Wv, Wqkvt, 256, 256, 768, 512);
  convT_kernel<<<dim3(8, 8, DEPTH),  dim3(32, 8), 0, stream>>>(Wo, Wot, 256, 256, 256, 0);
  convT_kernel<<<dim3(32, 8, DEPTH), dim3(32, 8), 0, stream>>>(W1, W1t, 256, 1024, 1024, 0);
  convT_kernel<<<dim3(8, 32, DEPTH), dim3(32, 8), 0, stream>>>(W2, W2t, 1024, 256, 256, 0);

  embed_kernel<<<dim3(E, B), 128, 0, stream>>>(user, item, utab, itab, cls, pos, x);

  for (int L = 0; L < DEPTH; ++L) {
    ln_kernel<<<BN / 4, 256, 0, stream>>>(x, h, ln1g + L * E, ln1b + L * E);
    gemm_f16<256, 768, EPI_QKV><<<dim3(6, 257), 256, 0, stream>>>(
        h, Wqkvt + (size_t)L * 768 * 256, bq + L * E, bk + L * E, bv + L * E, fq);
    attn_mfma<<<dim3(512, 2), 256, 0, stream>>>(qb, kb, vb, h);
    gemm_f16<256, 256, EPI_RESID><<<dim3(2, 257), 256, 0, stream>>>(
        h, Wot + (size_t)L * 256 * 256, bo + L * E, bo + L * E, bo + L * E, x);
    ln_kernel<<<BN / 4, 256, 0, stream>>>(x, h, ln2g + L * E, ln2b + L * E);
    gemm_f16<256, 1024, EPI_GELU><<<dim3(8, 257), 256, 0, stream>>>(
        h, W1t + (size_t)L * 1024 * 256, b1 + L * FFD, b1 + L * FFD, b1 + L * FFD, fq);
    gemm_f16<1024, 256, EPI_RESID><<<dim3(2, 257), 256, 0, stream>>>(
        fq, W2t + (size_t)L * 256 * 1024, b2 + L * E, b2 + L * E, b2 + L * E, x);
  }

  head_kernel<<<B, 256, 0, stream>>>(x, hg, hb, hW, hbias, out);
}